// Round 12
// baseline (314.161 us; speedup 1.0000x reference)
//
#include <hip/hip_runtime.h>
#include <math.h>

#define NPIX 1024   // H*W = 32*32

typedef __bf16 bf16x8 __attribute__((ext_vector_type(8)));
typedef float  f32x4  __attribute__((ext_vector_type(4)));

// ---------------------------------------------------------------------------
// bf16-MFMA conv1x1 GEMM: out[b,o,n] = sc[o]*(sum_c W[o,c]*in[b,c,n])+bi[o]
// (+res). 128x128 tile, K-step 32, 4 waves (2x2), wave tile 64x64 = 4x4
// frags of mfma_f32_16x16x32_bf16. LDS rows padded to 80 B -> 2-way banks.
// ---------------------------------------------------------------------------
__global__ __launch_bounds__(256) void conv1x1_mfma_kernel(
    const float* __restrict__ in, const float* __restrict__ W,
    const float* __restrict__ sc, const float* __restrict__ bi,
    const float* __restrict__ res, float* __restrict__ out,
    int O, int C) {
  const int b  = blockIdx.z;
  const int o0 = blockIdx.y << 7;
  const int n0 = blockIdx.x << 7;
  const float* inb  = in  + (size_t)b * C * NPIX;
  float*       outb = out + (size_t)b * O * NPIX;
  const float* resb = res ? res + (size_t)b * O * NPIX : nullptr;

  __shared__ __align__(16) __bf16 a_s[128][40];  // [o][k], 80-B pitch
  __shared__ __align__(16) __bf16 b_s[128][40];  // [n][k], 80-B pitch

  const int t    = threadIdx.x;
  const int lane = t & 63;
  const int wv   = t >> 6;
  const int wo   = (wv >> 1) << 6;   // wave o-offset: 0 / 64
  const int wn   = (wv & 1) << 6;    // wave n-offset: 0 / 64
  const int lr   = lane & 15;
  const int g    = lane >> 4;

  // staging roles
  const int ao = t >> 1, ak = (t & 1) << 4;   // A: row ao, k-half ak
  const int bn = t & 127, bk = (t >> 7) << 4; // B: row bn, k-half bk
  const float* wrow = &W[(size_t)(o0 + ao) * C];

  f32x4 acc[4][4];
#pragma unroll
  for (int m = 0; m < 4; ++m)
#pragma unroll
    for (int n = 0; n < 4; ++n) acc[m][n] = (f32x4){0.f, 0.f, 0.f, 0.f};

  for (int k0 = 0; k0 < C; k0 += 32) {
    __syncthreads();  // previous step's fragment reads done
    // ---- stage A: 16 f32 -> bf16, two 16-B LDS writes ----
    {
      const float* wp = wrow + k0 + ak;
#pragma unroll
      for (int half = 0; half < 2; ++half) {
        float4 lo = *(const float4*)&wp[half * 8];
        float4 hi = *(const float4*)&wp[half * 8 + 4];
        union { __bf16 h[8]; uint4 u; } pk;
        pk.h[0] = (__bf16)lo.x; pk.h[1] = (__bf16)lo.y;
        pk.h[2] = (__bf16)lo.z; pk.h[3] = (__bf16)lo.w;
        pk.h[4] = (__bf16)hi.x; pk.h[5] = (__bf16)hi.y;
        pk.h[6] = (__bf16)hi.z; pk.h[7] = (__bf16)hi.w;
        *(uint4*)((char*)&a_s[ao][ak] + half * 16) = pk.u;
      }
    }
    // ---- stage B: transpose [k][n] -> [n][k], 4x (4 loads -> 8-B write) ----
    {
#pragma unroll
      for (int p = 0; p < 4; ++p) {
        const int kk = k0 + bk + (p << 2);
        union { __bf16 h[4]; uint2 u; } pk;
        pk.h[0] = (__bf16)inb[(size_t)(kk + 0) * NPIX + n0 + bn];
        pk.h[1] = (__bf16)inb[(size_t)(kk + 1) * NPIX + n0 + bn];
        pk.h[2] = (__bf16)inb[(size_t)(kk + 2) * NPIX + n0 + bn];
        pk.h[3] = (__bf16)inb[(size_t)(kk + 3) * NPIX + n0 + bn];
        *(uint2*)((char*)&b_s[bn][bk] + (p << 3)) = pk.u;
      }
    }
    __syncthreads();
    // ---- fragments + 16 MFMAs ----
    bf16x8 af[4], bfr[4];
#pragma unroll
    for (int m = 0; m < 4; ++m)
      af[m] = *(const bf16x8*)((const char*)&a_s[wo + (m << 4) + lr][0] + (g << 4));
#pragma unroll
    for (int n = 0; n < 4; ++n)
      bfr[n] = *(const bf16x8*)((const char*)&b_s[wn + (n << 4) + lr][0] + (g << 4));
#pragma unroll
    for (int m = 0; m < 4; ++m)
#pragma unroll
      for (int n = 0; n < 4; ++n)
        acc[m][n] = __builtin_amdgcn_mfma_f32_16x16x32_bf16(
            af[m], bfr[n], acc[m][n], 0, 0, 0);
  }

  // ---- epilogue: scale/bias/residual in f32, coalesced stores ----
#pragma unroll
  for (int m = 0; m < 4; ++m) {
#pragma unroll
    for (int r = 0; r < 4; ++r) {
      const int o = o0 + wo + (m << 4) + (g << 2) + r;
      const float s  = sc ? sc[o] : 1.f;
      const float bb = bi ? bi[o] : 0.f;
      float* orow = &outb[(size_t)o * NPIX];
      const float* rrow = resb ? &resb[(size_t)o * NPIX] : nullptr;
#pragma unroll
      for (int n = 0; n < 4; ++n) {
        const int nn = n0 + wn + (n << 4) + lr;
        float v = fmaf(acc[m][n][r], s, bb);
        if (rrow) v += rrow[nn];
        orow[nn] = v;
      }
    }
  }
}

// ---------------------------------------------------------------------------
// bf16-MFMA flash attention, v5.
//  * QBLK=128: each block owns 128 queries (8 tiles/bh, 512 blocks); each
//    wave owns 32 queries via TWO Q/P fragment sets. K/V staging (unchanged
//    mechanics) now serves 2x the compute; KT frag reads reused across both
//    Q-frags; V frag reads serve both acc chains.
//  * exp2-domain softmax: Q pre-scaled by scale*log2e, exp2f (native v_exp).
//  * XCD-aware grid; KT/V XOR-swizzled tiles; wave-private LDS P round-trip.
// ---------------------------------------------------------------------------
__global__ __launch_bounds__(256) void attn_mfma_kernel(
    const float* __restrict__ qkv, float* __restrict__ outbuf) {
  const int L    = blockIdx.x;        // 0..511
  const int xcd  = L & 7;
  const int rr   = L >> 3;            // 0..63
  const int tile = rr & 7;
  const int bh   = xcd + ((rr >> 3) << 3);
  const int h    = bh & 3;
  const int b    = bh >> 2;
  const int n0   = tile << 7;
  const float scale2 = 0.25506002427548707f;  // (1/sqrt(32))*log2(e)
  const float* base = qkv + ((size_t)b * 512 + h * 128) * NPIX;

  __shared__ __align__(16) char kt_b[64 * 128];    // KT[m][c] bf16, XOR-swz
  __shared__ __align__(16) char v_b[64 * 128];     // V[d][m] bf16, XOR-swz
  __shared__ __align__(16) char p_b[4 * 32 * 128]; // P[q][m] bf16/wave, XOR-swz

  const int t    = threadIdx.x;
  const int w    = t >> 6;
  const int lane = t & 63;
  const int lq   = lane & 15;
  const int g    = lane >> 4;

  // Q B-frags (persistent): wave w owns queries n0+32w .. n0+32w+31
  bf16x8 qfA, qfB;
  {
    const float* qp = base + (size_t)(g << 3) * NPIX + n0 + (w << 5) + lq;
#pragma unroll
    for (int j = 0; j < 8; ++j) {
      qfA[j] = (__bf16)(qp[(size_t)j * NPIX] * scale2);
      qfB[j] = (__bf16)(qp[(size_t)j * NPIX + 16] * scale2);
    }
  }

  // KT staging roles: channel pair cp, spread rows rq+16i
  const int cp = t >> 4;             // 0..15
  const int rq = t & 15;             // 0..15
  const float* kr0 = base + (size_t)(32 + (cp << 1)) * NPIX;
  const float* kr1 = kr0 + NPIX;
  const int koff = (cp << 2) ^ ((rq & 7) << 4);
  // V staging roles: column slot vn, base row vr; rows vr+16i
  const int vn = t & 15;             // byte col = vn*8 (m = 4vn..4vn+3)
  const int vr = t >> 4;             // 0..15
  const float* vrp = base + (size_t)(64 + vr) * NPIX;

  // wave-private P region (32 rows x 128 B)
  char* pw = p_b + (w << 12);
  const int pswz = (lq & 7) << 4;

  float mA = -3.0e38f, lA = 0.f, mB = -3.0e38f, lB = 0.f;
  f32x4 accA0 = {0.f, 0.f, 0.f, 0.f}, accA1 = accA0, accA2 = accA0, accA3 = accA0;
  f32x4 accB0 = accA0, accB1 = accA0, accB2 = accA0, accB3 = accA0;

  for (int mt = 0; mt < 16; ++mt) {
    const int m0 = mt << 6;
    __syncthreads();  // previous tile's reads done before overwrite
    // ---- stage KT: 2 channels x 4 spread rows, 4-B word writes ----
#pragma unroll
    for (int i = 0; i < 4; ++i) {
      const int m = rq + (i << 4);
      union { __bf16 h2[2]; unsigned u; } pk;
      pk.h2[0] = (__bf16)kr0[m0 + m];
      pk.h2[1] = (__bf16)kr1[m0 + m];
      *(unsigned*)(kt_b + (m << 7) + koff) = pk.u;
    }
    // ---- stage V: 4 full rows per wave-instruction (conflict-free) ----
#pragma unroll
    for (int i = 0; i < 4; ++i) {
      const int vd = vr + (i << 4);
      float4 v4 = *(const float4*)&vrp[(size_t)(i << 4) * NPIX + m0 + (vn << 2)];
      union { __bf16 h[4]; uint2 u; } pk;
      pk.h[0] = (__bf16)v4.x; pk.h[1] = (__bf16)v4.y;
      pk.h[2] = (__bf16)v4.z; pk.h[3] = (__bf16)v4.w;
      *(uint2*)(v_b + (vd << 7) + ((vn << 3) ^ ((vd & 7) << 4))) = pk.u;
    }
    __syncthreads();

    // ---- QK^T (swapped, log2 domain): st*[tt] = S2^T[16tt+4g+r][q] ----
    f32x4 stA[4], stB[4];
#pragma unroll
    for (int tt = 0; tt < 4; ++tt) {
      const int m = (tt << 4) + lq;
      const bf16x8 kfrag = *(const bf16x8*)(
          kt_b + (m << 7) + ((g ^ (lq & 7)) << 4));
      stA[tt] = __builtin_amdgcn_mfma_f32_16x16x32_bf16(
          kfrag, qfA, (f32x4){0.f, 0.f, 0.f, 0.f}, 0, 0, 0);
      stB[tt] = __builtin_amdgcn_mfma_f32_16x16x32_bf16(
          kfrag, qfB, (f32x4){0.f, 0.f, 0.f, 0.f}, 0, 0, 0);
    }

    // ---- online softmax (log2 domain), per frag ----
    {
      float tmax = -3.0e38f;
#pragma unroll
      for (int tt = 0; tt < 4; ++tt)
#pragma unroll
        for (int r = 0; r < 4; ++r) tmax = fmaxf(tmax, stA[tt][r]);
      tmax = fmaxf(tmax, __shfl_xor(tmax, 16));
      tmax = fmaxf(tmax, __shfl_xor(tmax, 32));
      const float mnew  = fmaxf(mA, tmax);
      const float alpha = exp2f(mA - mnew);
      float ssum = 0.f;
#pragma unroll
      for (int tt = 0; tt < 4; ++tt)
#pragma unroll
        for (int r = 0; r < 4; ++r) {
          stA[tt][r] = exp2f(stA[tt][r] - mnew);
          ssum += stA[tt][r];
        }
      ssum += __shfl_xor(ssum, 16);
      ssum += __shfl_xor(ssum, 32);
      lA = lA * alpha + ssum;
      mA = mnew;
      accA0 *= alpha; accA1 *= alpha; accA2 *= alpha; accA3 *= alpha;
    }
    {
      float tmax = -3.0e38f;
#pragma unroll
      for (int tt = 0; tt < 4; ++tt)
#pragma unroll
        for (int r = 0; r < 4; ++r) tmax = fmaxf(tmax, stB[tt][r]);
      tmax = fmaxf(tmax, __shfl_xor(tmax, 16));
      tmax = fmaxf(tmax, __shfl_xor(tmax, 32));
      const float mnew  = fmaxf(mB, tmax);
      const float alpha = exp2f(mB - mnew);
      float ssum = 0.f;
#pragma unroll
      for (int tt = 0; tt < 4; ++tt)
#pragma unroll
        for (int r = 0; r < 4; ++r) {
          stB[tt][r] = exp2f(stB[tt][r] - mnew);
          ssum += stB[tt][r];
        }
      ssum += __shfl_xor(ssum, 16);
      ssum += __shfl_xor(ssum, 32);
      lB = lB * alpha + ssum;
      mB = mnew;
      accB0 *= alpha; accB1 *= alpha; accB2 *= alpha; accB3 *= alpha;
    }

    // ---- write P[q][m] (bf16) to wave-private LDS (rows lq / lq+16) ----
#pragma unroll
    for (int tt = 0; tt < 4; ++tt) {
      union { __bf16 h[4]; uint2 u; } pkA, pkB;
      pkA.h[0] = (__bf16)stA[tt][0]; pkA.h[1] = (__bf16)stA[tt][1];
      pkA.h[2] = (__bf16)stA[tt][2]; pkA.h[3] = (__bf16)stA[tt][3];
      pkB.h[0] = (__bf16)stB[tt][0]; pkB.h[1] = (__bf16)stB[tt][1];
      pkB.h[2] = (__bf16)stB[tt][2]; pkB.h[3] = (__bf16)stB[tt][3];
      const int cbyte = ((tt << 5) + (g << 3)) ^ pswz;
      *(uint2*)(pw + (lq << 7) + cbyte) = pkA.u;
      *(uint2*)(pw + ((lq + 16) << 7) + cbyte) = pkB.u;
    }

    // ---- PV: out^T += mfma(V-frag, P-frag); V frags serve both chains ----
#pragma unroll
    for (int s = 0; s < 2; ++s) {
      const int cbyte = ((s << 6) + (g << 4)) ^ pswz;
      const bf16x8 pfA = *(const bf16x8*)(pw + (lq << 7) + cbyte);
      const bf16x8 pfB = *(const bf16x8*)(pw + ((lq + 16) << 7) + cbyte);
      const int cb = ((g << 4) + (s << 6));
#pragma unroll
      for (int dt = 0; dt < 4; ++dt) {
        const int row = (dt << 4) + lq;
        const bf16x8 vfrag = *(const bf16x8*)(
            v_b + (row << 7) + (cb ^ ((lq & 7) << 4)));
        f32x4& aA = (dt == 0) ? accA0 : (dt == 1) ? accA1 : (dt == 2) ? accA2 : accA3;
        f32x4& aB = (dt == 0) ? accB0 : (dt == 1) ? accB1 : (dt == 2) ? accB2 : accB3;
        aA = __builtin_amdgcn_mfma_f32_16x16x32_bf16(vfrag, pfA, aA, 0, 0, 0);
        aB = __builtin_amdgcn_mfma_f32_16x16x32_bf16(vfrag, pfB, aB, 0, 0, 0);
      }
    }
  }

  // ---- epilogue: out[d][n] = acc^T / l ----
  const float invA = 1.f / lA, invB = 1.f / lB;
  float* opA = outbuf + ((size_t)b * 256 + h * 64) * NPIX + n0 + (w << 5) + lq;
  float* opB = opA + 16;
#pragma unroll
  for (int r = 0; r < 4; ++r) {
    opA[(size_t)(( 0) + (g << 2) + r) * NPIX] = accA0[r] * invA;
    opA[(size_t)((16) + (g << 2) + r) * NPIX] = accA1[r] * invA;
    opA[(size_t)((32) + (g << 2) + r) * NPIX] = accA2[r] * invA;
    opA[(size_t)((48) + (g << 2) + r) * NPIX] = accA3[r] * invA;
    opB[(size_t)(( 0) + (g << 2) + r) * NPIX] = accB0[r] * invB;
    opB[(size_t)((16) + (g << 2) + r) * NPIX] = accB1[r] * invB;
    opB[(size_t)((32) + (g << 2) + r) * NPIX] = accB2[r] * invB;
    opB[(size_t)((48) + (g << 2) + r) * NPIX] = accB3[r] * invB;
  }
}

// ---------------------------------------------------------------------------
// Depthwise 3x3 on v_img (= v slice of qkv) + affine; accumulate into att_buf.
// ---------------------------------------------------------------------------
__global__ __launch_bounds__(256) void pe_kernel(
    const float* __restrict__ qkv, const float* __restrict__ w,
    const float* __restrict__ s, const float* __restrict__ bi,
    float* __restrict__ att) {
  const int idx = blockIdx.x * 256 + threadIdx.x;
  const int pix = idx & 1023;
  const int ch  = (idx >> 10) & 255;
  const int b   = idx >> 18;
  const int hh = pix >> 5, ww = pix & 31;
  const int row = ((ch >> 6) * 128) + 64 + (ch & 63);
  const float* vimg = qkv + ((size_t)b * 512 + row) * NPIX;
  float acc = 0.f;
#pragma unroll
  for (int dy = -1; dy <= 1; ++dy)
#pragma unroll
    for (int dx = -1; dx <= 1; ++dx) {
      int y = hh + dy, x = ww + dx;
      if (y >= 0 && y < 32 && x >= 0 && x < 32)
        acc = fmaf(w[ch * 9 + (dy + 1) * 3 + (dx + 1)], vimg[(y << 5) + x], acc);
    }
  att[idx] += fmaf(acc, s[ch], bi[ch]);
}

// ---------------------------------------------------------------------------
// Depthwise 3x3 + GLU: one block per (b,c) plane, 34x34 zero-padded LDS tiles.
// g = gelu(dw(y1)) * dw(y2).
// ---------------------------------------------------------------------------
__global__ __launch_bounds__(256) void dwglu_kernel(
    const float* __restrict__ y, const float* __restrict__ w,
    float* __restrict__ g) {
  const int bid = blockIdx.x;        // b*512 + c
  const int c   = bid & 511;
  const int b   = bid >> 9;

  __shared__ float t1[34 * 34];
  __shared__ float t2[34 * 34];
  const int t = threadIdx.x;

  // zero-init (border = SAME zero padding)
  for (int i = t; i < 34 * 34; i += 256) { t1[i] = 0.f; t2[i] = 0.f; }
  __syncthreads();

  const float* y1 = y + ((size_t)b * 1024 + c) * NPIX;
  const float* y2 = y1 + (size_t)512 * NPIX;
  const int r  = t >> 3;            // 0..31
  const int cq = (t & 7) << 2;      // 0,4,..,28
  {
    float4 a1 = *(const float4*)&y1[(r << 5) + cq];
    float4 a2 = *(const float4*)&y2[(r << 5) + cq];
    const int base = (r + 1) * 34 + cq + 1;
    t1[base + 0] = a1.x; t1[base + 1] = a1.y;
    t1[base + 2] = a1.z; t1[base + 3] = a1.w;
    t2[base + 0] = a2.x; t2[base + 1] = a2.y;
    t2[base + 2] = a2.z; t2[base + 3] = a2.w;
  }
  __syncthreads();

  // weights to registers (block-uniform)
  const float* w1 = w + c * 9;
  const float* w2 = w + (512 + c) * 9;
  float W1[9], W2[9];
#pragma unroll
  for (int k = 0; k < 9; ++k) { W1[k] = w1[k]; W2[k] = w2[k]; }

  float4 res;
#pragma unroll
  for (int j = 0; j < 4; ++j) {
    const int x = cq + j;
    float s1 = 0.f, s2 = 0.f;
#pragma unroll
    for (int dy = 0; dy < 3; ++dy)
#pragma unroll
      for (int dx = 0; dx < 3; ++dx) {
        const int idx = (r + dy) * 34 + x + dx;
        const int k   = dy * 3 + dx;
        s1 = fmaf(W1[k], t1[idx], s1);
        s2 = fmaf(W2[k], t2[idx], s2);
      }
    const float ge = 0.5f * s1 * (1.f + erff(s1 * 0.70710678118654752f));
    ((float*)&res)[j] = ge * s2;
  }
  *(float4*)&g[((size_t)b * 512 + c) * NPIX + (r << 5) + cq] = res;
}

// ---------------------------------------------------------------------------
// Build per-channel 8x8 circular-conv kernel from the rfft2 filter.
// ---------------------------------------------------------------------------
__global__ __launch_bounds__(256) void kc_build(
    const float* __restrict__ filt, float* __restrict__ kc) {
  const int gid = blockIdx.x * 256 + threadIdx.x;
  const int c  = gid >> 6;
  const int da = (gid >> 3) & 7;
  const int db = gid & 7;
  const float* F = filt + c * 40;
  float acc = 0.f;
  for (int u = 0; u < 8; ++u)
    for (int v = 0; v <= 4; ++v) {
      const float wv = (v == 0 || v == 4) ? 1.f : 2.f;
      const int ph = (u * da + v * db) & 7;
      acc += wv * F[u * 5 + v] * cosf(0.78539816339744831f * (float)ph);
    }
  kc[gid] = acc * (1.f / 64.f);
}

// ---------------------------------------------------------------------------
// Apply per-channel 8x8 circular conv per spatial tile + final residual add.
// ---------------------------------------------------------------------------
__global__ __launch_bounds__(256) void fft_final_kernel(
    const float* __restrict__ yin, const float* __restrict__ x2,
    const float* __restrict__ kc, float* __restrict__ out) {
  const int bid = blockIdx.x;
  const int gq = bid & 3;
  const int c  = (bid >> 2) & 255;
  const int b  = bid >> 10;
  __shared__ float kc_s[64];
  __shared__ float tile_s[4][64];
  const int t = threadIdx.x;
  if (t < 64) kc_s[t] = kc[(c << 6) + t];
  const int tl   = t >> 6;
  const int tile = (gq << 2) + tl;
  const int hb = tile >> 2, wb = tile & 3;
  const int a = (t >> 3) & 7, bb2 = t & 7;
  const size_t pbase = ((size_t)b * 256 + c) * NPIX;
  const size_t off = pbase + (size_t)((hb << 3) + a) * 32 + (wb << 3) + bb2;
  tile_s[tl][(a << 3) + bb2] = yin[off];
  __syncthreads();
  float acc = 0.f;
#pragma unroll
  for (int ap = 0; ap < 8; ++ap)
#pragma unroll
    for (int bp = 0; bp < 8; ++bp)
      acc = fmaf(kc_s[(((a - ap) & 7) << 3) + ((bb2 - bp) & 7)],
                 tile_s[tl][(ap << 3) + bp], acc);
  out[off] = x2[off] + acc;
}

// ---------------------------------------------------------------------------
extern "C" void kernel_launch(void* const* d_in, const int* in_sizes, int n_in,
                              void* d_out, int out_size, void* d_ws, size_t ws_size,
                              hipStream_t stream) {
  const float* x      = (const float*)d_in[0];
  const float* qkv_w  = (const float*)d_in[1];
  const float* qkv_s  = (const float*)d_in[2];
  const float* qkv_b  = (const float*)d_in[3];
  const float* pe_w   = (const float*)d_in[4];
  const float* pe_s   = (const float*)d_in[5];
  const float* pe_b   = (const float*)d_in[6];
  const float* proj_w = (const float*)d_in[7];
  const float* proj_s = (const float*)d_in[8];
  const float* proj_b = (const float*)d_in[9];
  const float* pin_w  = (const float*)d_in[10];
  const float* dw_w   = (const float*)d_in[11];
  const float* filt   = (const float*)d_in[12];
  const float* pout_w = (const float*)d_in[13];
  float* out = (float*)d_out;
  float* ws  = (float*)d_ws;

  float* qkv_buf = ws;                   // 16*512*1024
  float* att_buf = ws + 8388608;         // 16*256*1024
  float* x2      = ws + 12582912;        // 16*256*1024
  float* y_pin   = ws + 16777216;        // 16*1024*1024
  float* g_buf   = ws;                   // reuse qkv region
  float* y_out   = ws + 8388608;         // reuse att region
  float* kc      = ws + 33554432;        // 256*64

  dim3 blk(256);
  kc_build<<<dim3(64), blk, 0, stream>>>(filt, kc);
  // qkv = affine(qkv_w @ x)            M=512  K=256
  conv1x1_mfma_kernel<<<dim3(8, 4, 16), blk, 0, stream>>>(
      x, qkv_w, qkv_s, qkv_b, nullptr, qkv_buf, 512, 256);
  attn_mfma_kernel<<<dim3(512), blk, 0, stream>>>(qkv_buf, att_buf);
  pe_kernel<<<dim3(16384), blk, 0, stream>>>(qkv_buf, pe_w, pe_s, pe_b, att_buf);
  // x2 = x + affine(proj_w @ att)      M=256  K=256
  conv1x1_mfma_kernel<<<dim3(8, 2, 16), blk, 0, stream>>>(
      att_buf, proj_w, proj_s, proj_b, x, x2, 256, 256);
  // y_pin = pin_w @ x2                 M=1024 K=256
  conv1x1_mfma_kernel<<<dim3(8, 8, 16), blk, 0, stream>>>(
      x2, pin_w, nullptr, nullptr, nullptr, y_pin, 1024, 256);
  dwglu_kernel<<<dim3(8192), blk, 0, stream>>>(y_pin, dw_w, g_buf);
  // y_out = pout_w @ g                 M=256  K=512
  conv1x1_mfma_kernel<<<dim3(8, 2, 16), blk, 0, stream>>>(
      g_buf, pout_w, nullptr, nullptr, nullptr, y_out, 256, 512);
  fft_final_kernel<<<dim3(16384), blk, 0, stream>>>(y_out, x2, kc, out);
}